// Round 1
// baseline (95.408 us; speedup 1.0000x reference)
//
#include <hip/hip_runtime.h>

#define BSZ   2
#define NBOX  6300
#define NATTR 85
#define NCLS  80
#define CAP   512   // per-(img,class) capacity; mean count ~39, std ~6 -> 512 is unreachable

// One wave (64 lanes) per box. Lanes cooperatively load the 85 attrs,
// reduce max/argmax over class scores (attrs 5..84) with first-index
// tiebreak (matches jnp.argmax), then lane 0 appends valid boxes to the
// per-(image,class) list and stores the raw max class score.
__global__ __launch_bounds__(256) void prep_kernel(
    const float* __restrict__ x,
    float* __restrict__ bms,      // [BSZ*NBOX] raw max class score
    int* __restrict__ ccount,     // [BSZ*NCLS]
    int* __restrict__ clist) {    // [BSZ*NCLS*CAP]
  int gid  = blockIdx.x * blockDim.x + threadIdx.x;
  int wave = gid >> 6;
  int lane = threadIdx.x & 63;
  if (wave >= BSZ * NBOX) return;

  const float* p = x + (long)wave * NATTR;
  float r0 = p[lane];                                    // attrs 0..63
  float r1 = (lane < NATTR - 64) ? p[64 + lane] : -1.0f; // attrs 64..84

  // candidate from this lane: class scores only (attr >= 5)
  float c0 = (lane >= 5) ? r0 : -1.0f;
  float v; int vi;
  if (r1 > c0) { v = r1; vi = 64 + lane; }   // equal -> keep lower index c0
  else         { v = c0; vi = lane; }

  // wave64 reduction: max value, lowest attr index among maxes
  for (int off = 32; off > 0; off >>= 1) {
    float ov = __shfl_down(v, off);
    int   oi = __shfl_down(vi, off);
    if (ov > v || (ov == v && oi < vi)) { v = ov; vi = oi; }
  }

  float obj = __shfl(r0, 4);   // attr 4 = objectness
  if (lane == 0) {
    bms[wave] = v;
    // valid = (obj > CONF) & (masked max > SCORE); masked == raw when conf true
    if (obj > 0.5f && v > 0.3f) {
      int img = wave / NBOX;
      int bi  = wave - img * NBOX;
      int cls = vi - 5;
      int cc  = img * NCLS + cls;
      int pos = atomicAdd(&ccount[cc], 1);
      if (pos < CAP) clist[cc * CAP + pos] = bi;
    }
  }
}

// One 64-thread block per (image, class). Greedy NMS restricted to one
// class is exactly equivalent to the reference's global greedy loop
// (suppression requires same_cls; invalid boxes never act).
__global__ __launch_bounds__(64) void nms_kernel(
    const float* __restrict__ x,
    const float* __restrict__ bms,
    const int* __restrict__ ccount,
    const int* __restrict__ clist,
    float* __restrict__ out) {
  __shared__ float sx1[CAP], sy1[CAP], sx2[CAP], sy2[CAP], ssc[CAP];
  __shared__ int   sbi[CAP];
  __shared__ int   order[CAP];
  __shared__ unsigned char keepS[CAP];

  int bc  = blockIdx.x;
  int img = bc / NCLS;
  int cls = bc - img * NCLS;
  int k   = ccount[bc];
  if (k > CAP) k = CAP;
  if (k == 0) return;
  int t = threadIdx.x;

  // load boxes of this class into LDS; corners computed exactly as ref:
  // x1 = x - w*0.5 (mul is exact halving -> no contraction hazard)
  for (int e = t; e < k; e += 64) {
    int bi = clist[bc * CAP + e];
    const float* p = x + ((long)img * NBOX + bi) * NATTR;
    float cx = p[0], cy = p[1], w = p[2], h = p[3], obj = p[4];
    float hw = w * 0.5f, hh = h * 0.5f;
    sx1[e] = cx - hw; sy1[e] = cy - hh;
    sx2[e] = cx + hw; sy2[e] = cy + hh;
    ssc[e] = obj; sbi[e] = bi;
  }
  __syncthreads();

  // rank sort by (score desc, original index asc) == stable argsort(-score)
  for (int e = t; e < k; e += 64) {
    float se = ssc[e]; int ie = sbi[e];
    int r = 0;
    for (int j = 0; j < k; j++) {
      float sj = ssc[j];
      r += (sj > se) || (sj == se && sbi[j] < ie);
    }
    order[r]  = e;
    keepS[e]  = 1;
  }
  __syncthreads();

  // greedy: in score order, a kept box suppresses later same-class boxes
  // with IoU >= 0.4 (exact ref arithmetic, IEEE fp32 div)
  for (int r = 0; r + 1 < k; r++) {
    if (keepS[r]) {                 // uniform read (LDS broadcast)
      int e = order[r];
      float X1 = sx1[e], Y1 = sy1[e], X2 = sx2[e], Y2 = sy2[e];
      float ar = (X2 - X1) * (Y2 - Y1);
      for (int rr = r + 1 + t; rr < k; rr += 64) {
        int e2 = order[rr];
        float iw = fminf(X2, sx2[e2]) - fmaxf(X1, sx1[e2]);
        float ih = fminf(Y2, sy2[e2]) - fmaxf(Y1, sy1[e2]);
        iw = fmaxf(iw, 0.0f); ih = fmaxf(ih, 0.0f);
        float inter = iw * ih;
        float a2 = (sx2[e2] - sx1[e2]) * (sy2[e2] - sy1[e2]);
        float iou = inter / (ar + a2 - inter + 1e-16f);
        if (iou >= 0.4f) keepS[rr] = 0;
      }
    }
    __syncthreads();
  }

  // write kept rows: [batch, x1, y1, x2, y2, p_obj, max_score, cls]
  for (int r = t; r < k; r += 64) {
    if (keepS[r]) {
      int e  = order[r];
      long g = (long)img * NBOX + sbi[e];
      float* o = out + g * 8;
      o[0] = (float)img;
      o[1] = sx1[e]; o[2] = sy1[e]; o[3] = sx2[e]; o[4] = sy2[e];
      o[5] = ssc[e];
      o[6] = bms[g];
      o[7] = (float)cls;
    }
  }
}

extern "C" void kernel_launch(void* const* d_in, const int* in_sizes, int n_in,
                              void* d_out, int out_size, void* d_ws, size_t ws_size,
                              hipStream_t stream) {
  const float* x = (const float*)d_in[0];
  float* out = (float*)d_out;

  float* bms   = (float*)d_ws;                 // 12600 floats
  int* ccount  = (int*)(bms + BSZ * NBOX);     // 160 ints
  int* clist   = ccount + BSZ * NCLS;          // 160*512 ints  (~370 KB total ws)

  hipMemsetAsync(ccount, 0, BSZ * NCLS * sizeof(int), stream);
  hipMemsetAsync(out, 0, (size_t)out_size * sizeof(float), stream);

  prep_kernel<<<(BSZ * NBOX * 64) / 256, 256, 0, stream>>>(x, bms, ccount, clist);
  nms_kernel<<<BSZ * NCLS, 64, 0, stream>>>(x, bms, ccount, clist, out);
}